// Round 7
// baseline (548.898 us; speedup 1.0000x reference)
//
#include <hip/hip_runtime.h>
#include <hip/hip_bf16.h>

namespace {

constexpr int T_TOK = 8192;      // B*S
constexpr int HDIM  = 1024;
constexpr int FDIM  = 3584;
constexpr int CAP_ROWS = 18432;  // T*K + 8*256 pad
constexpr int MAXMT = CAP_ROWS / 256;  // 72

typedef __bf16 bf16x8 __attribute__((ext_vector_type(8)));
typedef float  f32x4  __attribute__((ext_vector_type(4)));

__device__ inline unsigned short f2bf(float f) {
  union { float f; unsigned u; } a; a.f = f;
  unsigned r = a.u + 0x7fffu + ((a.u >> 16) & 1u);   // RTN-even
  return (unsigned short)(r >> 16);
}

typedef const __attribute__((address_space(1))) void* gptr_t;
typedef __attribute__((address_space(3))) void* lptr_t;
__device__ inline void gload_lds16(const void* g, void* l) {
  __builtin_amdgcn_global_load_lds((gptr_t)g, (lptr_t)l, 16, 0, 0);
}

#define MFMA16(a, b, c) __builtin_amdgcn_mfma_f32_16x16x32_bf16(a, b, c, 0, 0, 0)

// meta layout (ints): [0..7] cnt, [8..15] cnt2, [16..23] seg off (rows),
// [24] total padded rows, [25] ntiles(256), [32..103] tile->expert
__global__ __launch_bounds__(256) void k_router(
    const float* __restrict__ x, const float* __restrict__ gw,
    const float* __restrict__ gw2, float* __restrict__ logits_out,
    int* __restrict__ sel, float* __restrict__ wts)
{
  int t = blockIdx.x * 4 + (threadIdx.x >> 6);
  int lane = threadIdx.x & 63;
  if (t >= T_TOK) return;
  const float* xr = x + (size_t)t * HDIM;
  float acc[10];
#pragma unroll
  for (int e = 0; e < 10; ++e) acc[e] = 0.f;
#pragma unroll
  for (int it = 0; it < 4; ++it) {
    int base = it * 256 + lane * 4;
    float4 xv = *reinterpret_cast<const float4*>(xr + base);
#pragma unroll
    for (int e = 0; e < 8; ++e) {
      float4 g = *reinterpret_cast<const float4*>(gw + e * HDIM + base);
      acc[e] += xv.x * g.x + xv.y * g.y + xv.z * g.z + xv.w * g.w;
    }
#pragma unroll
    for (int e = 0; e < 2; ++e) {
      float4 g = *reinterpret_cast<const float4*>(gw2 + e * HDIM + base);
      acc[8 + e] += xv.x * g.x + xv.y * g.y + xv.z * g.z + xv.w * g.w;
    }
  }
#pragma unroll
  for (int e = 0; e < 10; ++e) {
#pragma unroll
    for (int off = 32; off > 0; off >>= 1)
      acc[e] += __shfl_xor(acc[e], off, 64);
  }
  if (lane == 0) {
    float* lo = logits_out + (size_t)t * 10;
#pragma unroll
    for (int e = 0; e < 10; ++e) lo[e] = acc[e];
    float mx = acc[0];
#pragma unroll
    for (int e = 1; e < 10; ++e) mx = fmaxf(mx, acc[e]);
    float p[10], s = 0.f;
#pragma unroll
    for (int e = 0; e < 10; ++e) { p[e] = __expf(acc[e] - mx); s += p[e]; }
    float inv = 1.f / s;
#pragma unroll
    for (int e = 0; e < 10; ++e) p[e] *= inv;
    int i0 = 0;
    for (int e = 1; e < 10; ++e) if (p[e] > p[i0]) i0 = e;
    int i1 = (i0 == 0) ? 1 : 0;
    for (int e = 0; e < 10; ++e) if (e != i0 && p[e] > p[i1]) i1 = e;
    float w0 = p[i0], w1 = p[i1];
    bool r0 = i0 < 8, r1 = i1 < 8;
    float den = (r0 ? w0 : 0.f) + (r1 ? w1 : 0.f);
    if (den == 0.f) den = 1.f;
    sel[t * 2]     = i0; wts[t * 2]     = r0 ? w0 / den : 0.f;
    sel[t * 2 + 1] = i1; wts[t * 2 + 1] = r1 ? w1 / den : 0.f;
  }
}

// Fused histogram + segment setup (single block), 256-row padding.
__global__ __launch_bounds__(256) void k_histseg(
    const int* __restrict__ sel, int* __restrict__ meta)
{
  __shared__ int part[256][8];
  __shared__ int s_tile0[9];
  int tid = threadIdx.x;
  int c[8];
#pragma unroll
  for (int e = 0; e < 8; ++e) c[e] = 0;
  for (int i = 0; i < 64; ++i) {
    int v = sel[i * 256 + tid];
#pragma unroll
    for (int e = 0; e < 8; ++e) c[e] += (v == e);
  }
#pragma unroll
  for (int e = 0; e < 8; ++e) part[tid][e] = c[e];
  __syncthreads();
  for (int s = 128; s >= 1; s >>= 1) {
    if (tid < s) {
#pragma unroll
      for (int e = 0; e < 8; ++e) part[tid][e] += part[tid + s][e];
    }
    __syncthreads();
  }
  if (tid == 0) {
    int off = 0;
    for (int e = 0; e < 8; ++e) {
      int cnt = part[0][e];
      meta[e] = cnt;
      meta[8 + e] = 0;
      meta[16 + e] = off;
      s_tile0[e] = off >> 8;
      off += (cnt + 255) & ~255;
    }
    meta[24] = off;
    meta[25] = off >> 8;
    s_tile0[8] = off >> 8;
  }
  __syncthreads();
  int nt = s_tile0[8];
  if (tid < nt) {
    int e = 0;
    while (s_tile0[e + 1] <= tid) ++e;
    meta[32 + tid] = e;
  }
}

__global__ __launch_bounds__(256) void k_zeropad(
    const int* __restrict__ meta, unsigned short* __restrict__ xg)
{
  int e = blockIdx.x >> 8, r = blockIdx.x & 255;
  int c = meta[e];
  int pad = (c + 255) & ~255;
  if (c + r >= pad) return;
  size_t row = (size_t)meta[16 + e] + c + r;
  reinterpret_cast<ushort4*>(xg + row * HDIM)[threadIdx.x] = ushort4{0, 0, 0, 0};
}

// Block-aggregated scatter (unchanged).
__global__ __launch_bounds__(256) void k_scatter(
    const float* __restrict__ x, const int* __restrict__ sel,
    int* __restrict__ meta, int* __restrict__ pair_row,
    unsigned short* __restrict__ xg)
{
  __shared__ int s_cnt[8];
  __shared__ int s_base[8];
  __shared__ int s_row[256];
  int tid = threadIdx.x;
  int pair0 = blockIdx.x * 256;
  if (tid < 8) s_cnt[tid] = 0;
  __syncthreads();
  int e = sel[pair0 + tid];
  int rank = -1;
  if (e < 8) rank = atomicAdd(&s_cnt[e], 1);
  __syncthreads();
  if (tid < 8) {
    int c = s_cnt[tid];
    s_base[tid] = c > 0 ? atomicAdd(&meta[8 + tid], c) : 0;
  }
  __syncthreads();
  int row = (e < 8) ? meta[16 + e] + s_base[e] + rank : -1;
  pair_row[pair0 + tid] = row;
  s_row[tid] = row;
  __syncthreads();
  int wid = tid >> 6, lane = tid & 63;
  for (int i = wid; i < 256; i += 4) {
    int r = s_row[i];
    if (r < 0) continue;
    const float* xr = x + (size_t)((pair0 + i) >> 1) * HDIM;
    unsigned short* dst = xg + (size_t)r * HDIM;
#pragma unroll
    for (int it = 0; it < 4; ++it) {
      int base = it * 256 + lane * 4;
      float4 v = *reinterpret_cast<const float4*>(xr + base);
      ushort4 o{f2bf(v.x), f2bf(v.y), f2bf(v.z), f2bf(v.w)};
      *reinterpret_cast<ushort4*>(dst + base) = o;
    }
  }
}

// fp32 -> bf16 weight-chunk convert (unchanged).
__global__ __launch_bounds__(256) void k_conv3(
    const float* __restrict__ s1, const float* __restrict__ s3,
    const float* __restrict__ s2,
    unsigned short* __restrict__ d1, unsigned short* __restrict__ d3,
    unsigned short* __restrict__ d2,
    long long total, long long rl13, long long ss13,
    long long rl2, long long ss2)
{
  long long i = ((long long)blockIdx.x * 256 + threadIdx.x) * 8;
  if (i >= total) return;
  const float* src; unsigned short* dst; long long rowlen, sstride;
  if (blockIdx.y == 0)      { src = s1; dst = d1; rowlen = rl13; sstride = ss13; }
  else if (blockIdx.y == 1) { src = s3; dst = d3; rowlen = rl13; sstride = ss13; }
  else                      { src = s2; dst = d2; rowlen = rl2;  sstride = ss2;  }
  const float* sp;
  if (rowlen == sstride) {
    sp = src + i;
  } else {
    long long r = i / rowlen, c = i - r * rowlen;
    sp = src + r * sstride + c;
  }
  float4 a = reinterpret_cast<const float4*>(sp)[0];
  float4 b = reinterpret_cast<const float4*>(sp)[1];
  ushort4* d = reinterpret_cast<ushort4*>(dst + i);
  d[0] = ushort4{f2bf(a.x), f2bf(a.y), f2bf(a.z), f2bf(a.w)};
  d[1] = ushort4{f2bf(b.x), f2bf(b.y), f2bf(b.z), f2bf(b.w)};
}

// ---------------------------------------------------------------------------
// gemm1: hg = silu(xg @ wc1^T) * (xg @ wc3^T).  256M x 128N fused dual-B.
// 8 waves (512 thr), BK=64, 2-buffer LDS (128 KB), 4 phases x 16 MFMA per
// K-tile, stage-next-tile spread over phases 0-1, vmcnt(0) once per tile.
// XOR swizzle (col16 ^= row&7) via pre-swizzled source + XOR'd ds_read.
__global__ __launch_bounds__(512, 2) void k_gemm1(
    const unsigned short* __restrict__ xg,
    const unsigned short* __restrict__ wc1,
    const unsigned short* __restrict__ wc3,
    unsigned short* __restrict__ hg,
    const int* __restrict__ meta, int Fc)
{
  __shared__ __attribute__((aligned(128))) char lds[131072];
  // per buffer (stride 65536): A-half0 @0, A-half1 @16384, B1 @32768, B3 @49152

  int mt = blockIdx.y;
  if (mt >= meta[25]) return;
  int e = meta[32 + mt];
  int mrow0 = mt * 256;
  int fl0 = blockIdx.x * 128;

  int tid = threadIdx.x, lane = tid & 63, wid = tid >> 6;
  int lr = lane & 15, lg = lane >> 4;
  int wr = wid >> 2, wc = wid & 3;

  f32x4 acc1[8][2], acc3[8][2];
  const f32x4 zero = {0.f, 0.f, 0.f, 0.f};
#pragma unroll
  for (int m = 0; m < 8; ++m)
#pragma unroll
    for (int n = 0; n < 2; ++n) { acc1[m][n] = zero; acc3[m][n] = zero; }

  // staging: chunk = q*512+tid per 16KB half; row = q*64 + (tid>>3)
  int r0 = tid >> 3;
  int csw = ((tid & 7) ^ (r0 & 7)) * 8;    // pre-swizzled src col (elements)
  int dst0 = tid * 16;

  const unsigned short* pa[4];   // A halves h=0,1 x q=0,1
  const unsigned short* pb1[2];
  const unsigned short* pb3[2];
  {
    const unsigned short* Ab  = xg + (size_t)mrow0 * HDIM;
    const unsigned short* B1b = wc1 + ((size_t)e * Fc + fl0) * HDIM;
    const unsigned short* B3b = wc3 + ((size_t)e * Fc + fl0) * HDIM;
#pragma unroll
    for (int h = 0; h < 2; ++h)
#pragma unroll
      for (int q = 0; q < 2; ++q)
        pa[h * 2 + q] = Ab + (size_t)(h * 128 + q * 64 + r0) * HDIM + csw;
#pragma unroll
    for (int q = 0; q < 2; ++q) {
      pb1[q] = B1b + (size_t)(q * 64 + r0) * HDIM + csw;
      pb3[q] = B3b + (size_t)(q * 64 + r0) * HDIM + csw;
    }
  }

  auto STAGE_A = [&](int buf) {
    char* b = lds + buf * 65536;
#pragma unroll
    for (int i = 0; i < 4; ++i) {
      gload_lds16(pa[i], b + (i >> 1) * 16384 + (i & 1) * 8192 + dst0);
      pa[i] += 64;
    }
  };
  auto STAGE_B = [&](int buf) {
    char* b = lds + buf * 65536;
#pragma unroll
    for (int q = 0; q < 2; ++q) {
      gload_lds16(pb1[q], b + 32768 + q * 8192 + dst0);
      pb1[q] += 64;
      gload_lds16(pb3[q], b + 49152 + q * 8192 + dst0);
      pb3[q] += 64;
    }
  };

  const int fxor = (lr & 7) << 4;
  bf16x8 b1f[2], b3f[2];

  auto PHASE = [&](int buf, int kk, int mh, bool ldB) {
    const char* bb = lds + buf * 65536;
    const char* ab = bb + wr * 16384;
    int kbyte = (kk * 64 + lg * 16) ^ fxor;
    bf16x8 af[4];
#pragma unroll
    for (int i = 0; i < 4; ++i) {
      int ra = (mh * 4 + i) * 16 + lr;
      af[i] = *reinterpret_cast<const bf16x8*>(ab + ra * 128 + kbyte);
    }
    if (ldB) {
#pragma unroll
      for (int n = 0; n < 2; ++n) {
        int off = (wc * 32 + n * 16 + lr) * 128 + kbyte;
        b1f[n] = *reinterpret_cast<const bf16x8*>(bb + 32768 + off);
        b3f[n] = *reinterpret_cast<const bf16x8*>(bb + 49152 + off);
      }
    }
    __builtin_amdgcn_s_barrier();
    asm volatile("s_waitcnt lgkmcnt(0)" ::: "memory");
    __builtin_amdgcn_sched_barrier(0);
    __builtin_amdgcn_s_setprio(1);
#pragma unroll
    for (int i = 0; i < 4; ++i)
#pragma unroll
      for (int n = 0; n < 2; ++n) {
        acc1[mh * 4 + i][n] = MFMA16(af[i], b1f[n], acc1[mh * 4 + i][n]);
        acc3[mh * 4 + i][n] = MFMA16(af[i], b3f[n], acc3[mh * 4 + i][n]);
      }
    __builtin_amdgcn_s_setprio(0);
  };

  constexpr int NT = HDIM / 64;  // 16
  STAGE_A(0); STAGE_B(0);
  asm volatile("s_waitcnt vmcnt(0)" ::: "memory");
  __builtin_amdgcn_s_barrier();
#pragma unroll 1
  for (int t = 0; t < NT; ++t) {
    int c = t & 1;
    bool st = (t < NT - 1);
    if (st) STAGE_A(c ^ 1);
    PHASE(c, 0, 0, true);
    __builtin_amdgcn_s_barrier();
    if (st) STAGE_B(c ^ 1);
    PHASE(c, 0, 1, false);
    __builtin_amdgcn_s_barrier();
    PHASE(c, 1, 0, true);
    __builtin_amdgcn_s_barrier();
    PHASE(c, 1, 1, false);
    asm volatile("s_waitcnt vmcnt(0)" ::: "memory");
    __builtin_amdgcn_s_barrier();
  }

  // epilogue: silu(acc1)*acc3 -> bf16 hg
#pragma unroll
  for (int m = 0; m < 8; ++m)
#pragma unroll
    for (int n = 0; n < 2; ++n) {
      int gcol = fl0 + wc * 32 + n * 16 + lr;
#pragma unroll
      for (int j = 0; j < 4; ++j) {
        int grow = mrow0 + wr * 128 + m * 16 + lg * 4 + j;
        float s1 = acc1[m][n][j];
        float s3 = acc3[m][n][j];
        float h = s1 / (1.f + __expf(-s1)) * s3;
        hg[(size_t)grow * Fc + gcol] = f2bf(h);
      }
    }
}

// ---------------------------------------------------------------------------
// gemm2: yrows(+)= hg @ wc2^T.  256M x 128N single-B, same schedule shape
// (4 phases x 8 MFMA), LDS 96 KB (A 32KB + B 16KB per buffer).
__global__ __launch_bounds__(512, 2) void k_gemm2(
    const unsigned short* __restrict__ hg,
    const unsigned short* __restrict__ wc2,
    float* __restrict__ yrows, const int* __restrict__ meta,
    int Fc, int first)
{
  __shared__ __attribute__((aligned(128))) char lds[98304];
  // per buffer (stride 49152): A-half0 @0, A-half1 @16384, B @32768

  int mt = blockIdx.y;
  if (mt >= meta[25]) return;
  int e = meta[32 + mt];
  int mrow0 = mt * 256;
  int hcol0 = blockIdx.x * 128;

  int tid = threadIdx.x, lane = tid & 63, wid = tid >> 6;
  int lr = lane & 15, lg = lane >> 4;
  int wr = wid >> 2, wc = wid & 3;

  f32x4 acc[8][2];
  const f32x4 zero = {0.f, 0.f, 0.f, 0.f};
#pragma unroll
  for (int m = 0; m < 8; ++m)
#pragma unroll
    for (int n = 0; n < 2; ++n) acc[m][n] = zero;

  int r0 = tid >> 3;
  int csw = ((tid & 7) ^ (r0 & 7)) * 8;
  int dst0 = tid * 16;

  const unsigned short* pa[4];
  const unsigned short* pb[2];
  {
    const unsigned short* Ab = hg + (size_t)mrow0 * Fc;
    const unsigned short* Bb = wc2 + ((size_t)e * HDIM + hcol0) * Fc;
#pragma unroll
    for (int h = 0; h < 2; ++h)
#pragma unroll
      for (int q = 0; q < 2; ++q)
        pa[h * 2 + q] = Ab + (size_t)(h * 128 + q * 64 + r0) * Fc + csw;
#pragma unroll
    for (int q = 0; q < 2; ++q)
      pb[q] = Bb + (size_t)(q * 64 + r0) * Fc + csw;
  }

  auto STAGE_A = [&](int buf) {
    char* b = lds + buf * 49152;
#pragma unroll
    for (int i = 0; i < 4; ++i) {
      gload_lds16(pa[i], b + (i >> 1) * 16384 + (i & 1) * 8192 + dst0);
      pa[i] += 64;
    }
  };
  auto STAGE_B = [&](int buf) {
    char* b = lds + buf * 49152;
#pragma unroll
    for (int q = 0; q < 2; ++q) {
      gload_lds16(pb[q], b + 32768 + q * 8192 + dst0);
      pb[q] += 64;
    }
  };

  const int fxor = (lr & 7) << 4;
  bf16x8 bf[2];

  auto PHASE = [&](int buf, int kk, int mh, bool ldB) {
    const char* bb = lds + buf * 49152;
    const char* ab = bb + wr * 16384;
    int kbyte = (kk * 64 + lg * 16) ^ fxor;
    bf16x8 af[4];
#pragma unroll
    for (int i = 0; i < 4; ++i) {
      int ra = (mh * 4 + i) * 16 + lr;
      af[i] = *reinterpret_cast<const bf16x8*>(ab + ra * 128 + kbyte);
    }
    if (ldB) {
#pragma unroll
      for (int n = 0; n < 2; ++n) {
        int off = (wc * 32 + n * 16 + lr) * 128 + kbyte;
        bf[n] = *reinterpret_cast<const bf16x8*>(bb + 32768 + off);
      }
    }
    __builtin_amdgcn_s_barrier();
    asm volatile("s_waitcnt lgkmcnt(0)" ::: "memory");
    __builtin_amdgcn_sched_barrier(0);
    __builtin_amdgcn_s_setprio(1);
#pragma unroll
    for (int i = 0; i < 4; ++i)
#pragma unroll
      for (int n = 0; n < 2; ++n)
        acc[mh * 4 + i][n] = MFMA16(af[i], bf[n], acc[mh * 4 + i][n]);
    __builtin_amdgcn_s_setprio(0);
  };

  int NT = Fc / 64;
  STAGE_A(0); STAGE_B(0);
  asm volatile("s_waitcnt vmcnt(0)" ::: "memory");
  __builtin_amdgcn_s_barrier();
#pragma unroll 1
  for (int t = 0; t < NT; ++t) {
    int c = t & 1;
    bool st = (t < NT - 1);
    if (st) STAGE_A(c ^ 1);
    PHASE(c, 0, 0, true);
    __builtin_amdgcn_s_barrier();
    if (st) STAGE_B(c ^ 1);
    PHASE(c, 0, 1, false);
    __builtin_amdgcn_s_barrier();
    PHASE(c, 1, 0, true);
    __builtin_amdgcn_s_barrier();
    PHASE(c, 1, 1, false);
    asm volatile("s_waitcnt vmcnt(0)" ::: "memory");
    __builtin_amdgcn_s_barrier();
  }

#pragma unroll
  for (int m = 0; m < 8; ++m)
#pragma unroll
    for (int n = 0; n < 2; ++n) {
      int gcol = hcol0 + wc * 32 + n * 16 + lr;
#pragma unroll
      for (int j = 0; j < 4; ++j) {
        int grow = mrow0 + wr * 128 + m * 16 + lg * 4 + j;
        float* yp = yrows + (size_t)grow * HDIM + gcol;
        float v = acc[m][n][j];
        if (first) *yp = v; else *yp += v;
      }
    }
}

__global__ __launch_bounds__(256) void k_combine(
    const float* __restrict__ yrows, const int* __restrict__ pair_row,
    const float* __restrict__ wts, float* __restrict__ out)
{
  int t = blockIdx.x * 4 + (threadIdx.x >> 6);
  int lane = threadIdx.x & 63;
  if (t >= T_TOK) return;
  int r0 = pair_row[t * 2], r1 = pair_row[t * 2 + 1];
  float w0 = (r0 >= 0) ? wts[t * 2] : 0.f;
  float w1 = (r1 >= 0) ? wts[t * 2 + 1] : 0.f;
  const float* y0 = yrows + (size_t)(r0 >= 0 ? r0 : 0) * HDIM;
  const float* y1 = yrows + (size_t)(r1 >= 0 ? r1 : 0) * HDIM;
  float* op = out + (size_t)t * HDIM;
#pragma unroll
  for (int it = 0; it < 4; ++it) {
    int base = it * 256 + lane * 4;
    float4 a = *reinterpret_cast<const float4*>(y0 + base);
    float4 b = *reinterpret_cast<const float4*>(y1 + base);
    float4 r{w0 * a.x + w1 * b.x, w0 * a.y + w1 * b.y,
             w0 * a.z + w1 * b.z, w0 * a.w + w1 * b.w};
    *reinterpret_cast<float4*>(op + base) = r;
  }
}

}  // namespace

extern "C" void kernel_launch(void* const* d_in, const int* in_sizes, int n_in,
                              void* d_out, int out_size, void* d_ws, size_t ws_size,
                              hipStream_t stream)
{
  const float* x   = (const float*)d_in[0];
  const float* gw  = (const float*)d_in[1];
  const float* gw2 = (const float*)d_in[2];
  const float* w1  = (const float*)d_in[3];
  const float* w2  = (const float*)d_in[4];
  const float* w3  = (const float*)d_in[5];
  float* out = (float*)d_out;
  float* logits_out = out + (size_t)T_TOK * HDIM;

  char* p = (char*)d_ws;
  int* meta = (int*)p;            p += 1024;
  int* sel = (int*)p;             p += T_TOK * 2 * sizeof(int);
  float* wts = (float*)p;         p += T_TOK * 2 * sizeof(float);
  int* pair_row = (int*)p;        p += T_TOK * 2 * sizeof(int);
  unsigned short* xg = (unsigned short*)p;  p += (size_t)CAP_ROWS * HDIM * 2;
  float* yrows = (float*)p;                 p += (size_t)CAP_ROWS * HDIM * 4;
  size_t fixed = (size_t)(p - (char*)d_ws);

  // per-chunk: wc1 = wc3 = wc2 = 16384*Fc bytes; hg = 36864*Fc bytes.
  int nf = 28;
  const int opts[6] = {1, 2, 4, 7, 14, 28};
  for (int i = 0; i < 6; ++i) {
    size_t Fc_i = FDIM / opts[i];
    size_t need = fixed + 3 * 16384 * Fc_i + (size_t)CAP_ROWS * Fc_i * 2;
    if (need <= ws_size) { nf = opts[i]; break; }
  }
  int Fc = FDIM / nf;

  unsigned short* wc1 = (unsigned short*)p;  p += (size_t)16384 * Fc;
  unsigned short* wc3 = (unsigned short*)p;  p += (size_t)16384 * Fc;
  unsigned short* wc2 = (unsigned short*)p;  p += (size_t)16384 * Fc;
  unsigned short* hg  = (unsigned short*)p;

  k_router<<<T_TOK / 4, 256, 0, stream>>>(x, gw, gw2, logits_out, sel, wts);
  k_histseg<<<1, 256, 0, stream>>>(sel, meta);
  k_zeropad<<<2048, 256, 0, stream>>>(meta, xg);
  k_scatter<<<T_TOK * 2 / 256, 256, 0, stream>>>(x, sel, meta, pair_row, xg);

  long long total = 8LL * Fc * HDIM;
  int ncb = (int)(total / 8 / 256);
  for (int c = 0; c < nf; ++c) {
    long long c0 = (long long)c * Fc;
    k_conv3<<<dim3(ncb, 3), 256, 0, stream>>>(
        w1 + c0 * HDIM, w3 + c0 * HDIM, w2 + c0, wc1, wc3, wc2,
        total, (long long)Fc * HDIM, (long long)FDIM * HDIM,
        (long long)Fc, (long long)FDIM);

    k_gemm1<<<dim3(Fc / 128, MAXMT), 512, 0, stream>>>(xg, wc1, wc3, hg, meta, Fc);
    k_gemm2<<<dim3(HDIM / 128, MAXMT), 512, 0, stream>>>(hg, wc2, yrows, meta, Fc, c == 0 ? 1 : 0);
  }
  k_combine<<<T_TOK / 4, 256, 0, stream>>>(yrows, pair_row, wts, out);
}

// Round 8
// 537.542 us; speedup vs baseline: 1.0211x; 1.0211x over previous
//
#include <hip/hip_runtime.h>
#include <hip/hip_bf16.h>

namespace {

constexpr int T_TOK = 8192;      // B*S
constexpr int HDIM  = 1024;
constexpr int FDIM  = 3584;
constexpr int CAP_ROWS = 18432;  // T*K + 8*256 pad
constexpr int MAXMT = CAP_ROWS / 256;  // 72

typedef __bf16 bf16x8 __attribute__((ext_vector_type(8)));
typedef float  f32x4  __attribute__((ext_vector_type(4)));

__device__ inline unsigned short f2bf(float f) {
  union { float f; unsigned u; } a; a.f = f;
  unsigned r = a.u + 0x7fffu + ((a.u >> 16) & 1u);   // RTN-even
  return (unsigned short)(r >> 16);
}

typedef const __attribute__((address_space(1))) void* gptr_t;
typedef __attribute__((address_space(3))) void* lptr_t;
__device__ inline void gload_lds16(const void* g, void* l) {
  __builtin_amdgcn_global_load_lds((gptr_t)g, (lptr_t)l, 16, 0, 0);
}

#define MFMA16(a, b, c) __builtin_amdgcn_mfma_f32_16x16x32_bf16(a, b, c, 0, 0, 0)

// meta layout (ints): [0..7] cnt, [8..15] cnt2, [16..23] seg off (rows),
// [24] total padded rows, [25] ntiles(256), [32..103] tile->expert
__global__ __launch_bounds__(256) void k_router(
    const float* __restrict__ x, const float* __restrict__ gw,
    const float* __restrict__ gw2, float* __restrict__ logits_out,
    int* __restrict__ sel, float* __restrict__ wts)
{
  int t = blockIdx.x * 4 + (threadIdx.x >> 6);
  int lane = threadIdx.x & 63;
  if (t >= T_TOK) return;
  const float* xr = x + (size_t)t * HDIM;
  float acc[10];
#pragma unroll
  for (int e = 0; e < 10; ++e) acc[e] = 0.f;
#pragma unroll
  for (int it = 0; it < 4; ++it) {
    int base = it * 256 + lane * 4;
    float4 xv = *reinterpret_cast<const float4*>(xr + base);
#pragma unroll
    for (int e = 0; e < 8; ++e) {
      float4 g = *reinterpret_cast<const float4*>(gw + e * HDIM + base);
      acc[e] += xv.x * g.x + xv.y * g.y + xv.z * g.z + xv.w * g.w;
    }
#pragma unroll
    for (int e = 0; e < 2; ++e) {
      float4 g = *reinterpret_cast<const float4*>(gw2 + e * HDIM + base);
      acc[8 + e] += xv.x * g.x + xv.y * g.y + xv.z * g.z + xv.w * g.w;
    }
  }
#pragma unroll
  for (int e = 0; e < 10; ++e) {
#pragma unroll
    for (int off = 32; off > 0; off >>= 1)
      acc[e] += __shfl_xor(acc[e], off, 64);
  }
  if (lane == 0) {
    float* lo = logits_out + (size_t)t * 10;
#pragma unroll
    for (int e = 0; e < 10; ++e) lo[e] = acc[e];
    float mx = acc[0];
#pragma unroll
    for (int e = 1; e < 10; ++e) mx = fmaxf(mx, acc[e]);
    float p[10], s = 0.f;
#pragma unroll
    for (int e = 0; e < 10; ++e) { p[e] = __expf(acc[e] - mx); s += p[e]; }
    float inv = 1.f / s;
#pragma unroll
    for (int e = 0; e < 10; ++e) p[e] *= inv;
    int i0 = 0;
    for (int e = 1; e < 10; ++e) if (p[e] > p[i0]) i0 = e;
    int i1 = (i0 == 0) ? 1 : 0;
    for (int e = 0; e < 10; ++e) if (e != i0 && p[e] > p[i1]) i1 = e;
    float w0 = p[i0], w1 = p[i1];
    bool r0 = i0 < 8, r1 = i1 < 8;
    float den = (r0 ? w0 : 0.f) + (r1 ? w1 : 0.f);
    if (den == 0.f) den = 1.f;
    sel[t * 2]     = i0; wts[t * 2]     = r0 ? w0 / den : 0.f;
    sel[t * 2 + 1] = i1; wts[t * 2 + 1] = r1 ? w1 / den : 0.f;
  }
}

// Fused histogram + segment setup (single block), 256-row padding.
__global__ __launch_bounds__(256) void k_histseg(
    const int* __restrict__ sel, int* __restrict__ meta)
{
  __shared__ int part[256][8];
  __shared__ int s_tile0[9];
  int tid = threadIdx.x;
  int c[8];
#pragma unroll
  for (int e = 0; e < 8; ++e) c[e] = 0;
  for (int i = 0; i < 64; ++i) {
    int v = sel[i * 256 + tid];
#pragma unroll
    for (int e = 0; e < 8; ++e) c[e] += (v == e);
  }
#pragma unroll
  for (int e = 0; e < 8; ++e) part[tid][e] = c[e];
  __syncthreads();
  for (int s = 128; s >= 1; s >>= 1) {
    if (tid < s) {
#pragma unroll
      for (int e = 0; e < 8; ++e) part[tid][e] += part[tid + s][e];
    }
    __syncthreads();
  }
  if (tid == 0) {
    int off = 0;
    for (int e = 0; e < 8; ++e) {
      int cnt = part[0][e];
      meta[e] = cnt;
      meta[8 + e] = 0;
      meta[16 + e] = off;
      s_tile0[e] = off >> 8;
      off += (cnt + 255) & ~255;
    }
    meta[24] = off;
    meta[25] = off >> 8;
    s_tile0[8] = off >> 8;
  }
  __syncthreads();
  int nt = s_tile0[8];
  if (tid < nt) {
    int e = 0;
    while (s_tile0[e + 1] <= tid) ++e;
    meta[32 + tid] = e;
  }
}

__global__ __launch_bounds__(256) void k_zeropad(
    const int* __restrict__ meta, unsigned short* __restrict__ xg)
{
  int e = blockIdx.x >> 8, r = blockIdx.x & 255;
  int c = meta[e];
  int pad = (c + 255) & ~255;
  if (c + r >= pad) return;
  size_t row = (size_t)meta[16 + e] + c + r;
  reinterpret_cast<ushort4*>(xg + row * HDIM)[threadIdx.x] = ushort4{0, 0, 0, 0};
}

// Block-aggregated scatter (unchanged).
__global__ __launch_bounds__(256) void k_scatter(
    const float* __restrict__ x, const int* __restrict__ sel,
    int* __restrict__ meta, int* __restrict__ pair_row,
    unsigned short* __restrict__ xg)
{
  __shared__ int s_cnt[8];
  __shared__ int s_base[8];
  __shared__ int s_row[256];
  int tid = threadIdx.x;
  int pair0 = blockIdx.x * 256;
  if (tid < 8) s_cnt[tid] = 0;
  __syncthreads();
  int e = sel[pair0 + tid];
  int rank = -1;
  if (e < 8) rank = atomicAdd(&s_cnt[e], 1);
  __syncthreads();
  if (tid < 8) {
    int c = s_cnt[tid];
    s_base[tid] = c > 0 ? atomicAdd(&meta[8 + tid], c) : 0;
  }
  __syncthreads();
  int row = (e < 8) ? meta[16 + e] + s_base[e] + rank : -1;
  pair_row[pair0 + tid] = row;
  s_row[tid] = row;
  __syncthreads();
  int wid = tid >> 6, lane = tid & 63;
  for (int i = wid; i < 256; i += 4) {
    int r = s_row[i];
    if (r < 0) continue;
    const float* xr = x + (size_t)((pair0 + i) >> 1) * HDIM;
    unsigned short* dst = xg + (size_t)r * HDIM;
#pragma unroll
    for (int it = 0; it < 4; ++it) {
      int base = it * 256 + lane * 4;
      float4 v = *reinterpret_cast<const float4*>(xr + base);
      ushort4 o{f2bf(v.x), f2bf(v.y), f2bf(v.z), f2bf(v.w)};
      *reinterpret_cast<ushort4*>(dst + base) = o;
    }
  }
}

// fp32 -> bf16 weight-chunk convert (unchanged).
__global__ __launch_bounds__(256) void k_conv3(
    const float* __restrict__ s1, const float* __restrict__ s3,
    const float* __restrict__ s2,
    unsigned short* __restrict__ d1, unsigned short* __restrict__ d3,
    unsigned short* __restrict__ d2,
    long long total, long long rl13, long long ss13,
    long long rl2, long long ss2)
{
  long long i = ((long long)blockIdx.x * 256 + threadIdx.x) * 8;
  if (i >= total) return;
  const float* src; unsigned short* dst; long long rowlen, sstride;
  if (blockIdx.y == 0)      { src = s1; dst = d1; rowlen = rl13; sstride = ss13; }
  else if (blockIdx.y == 1) { src = s3; dst = d3; rowlen = rl13; sstride = ss13; }
  else                      { src = s2; dst = d2; rowlen = rl2;  sstride = ss2;  }
  const float* sp;
  if (rowlen == sstride) {
    sp = src + i;
  } else {
    long long r = i / rowlen, c = i - r * rowlen;
    sp = src + r * sstride + c;
  }
  float4 a = reinterpret_cast<const float4*>(sp)[0];
  float4 b = reinterpret_cast<const float4*>(sp)[1];
  ushort4* d = reinterpret_cast<ushort4*>(dst + i);
  d[0] = ushort4{f2bf(a.x), f2bf(a.y), f2bf(a.z), f2bf(a.w)};
  d[1] = ushort4{f2bf(b.x), f2bf(b.y), f2bf(b.z), f2bf(b.w)};
}

// ---------------------------------------------------------------------------
// gemm1: hg = silu(xg @ wc1^T) * (xg @ wc3^T).  256M x 128N fused dual-B.
// 8 waves, BK=64, 2-buffer LDS, 4 phases x 16 MFMA per K-tile.
// COUNTED vmcnt (T4): STAGE_A(next) issued, then vmcnt(4) waits only for
// stage(cur) — the 4 newest loads stay in flight across the whole K-tile.
// No vmcnt(0) drain in the main loop.
__global__ __launch_bounds__(512, 2) void k_gemm1(
    const unsigned short* __restrict__ xg,
    const unsigned short* __restrict__ wc1,
    const unsigned short* __restrict__ wc3,
    unsigned short* __restrict__ hg,
    const int* __restrict__ meta, int Fc)
{
  __shared__ __attribute__((aligned(128))) char lds[131072];
  // per buffer (stride 65536): A-half0 @0, A-half1 @16384, B1 @32768, B3 @49152

  int mt = blockIdx.y;
  if (mt >= meta[25]) return;
  int e = meta[32 + mt];
  int mrow0 = mt * 256;
  int fl0 = blockIdx.x * 128;

  int tid = threadIdx.x, lane = tid & 63, wid = tid >> 6;
  int lr = lane & 15, lg = lane >> 4;
  int wr = wid >> 2, wc = wid & 3;

  f32x4 acc1[8][2], acc3[8][2];
  const f32x4 zero = {0.f, 0.f, 0.f, 0.f};
#pragma unroll
  for (int m = 0; m < 8; ++m)
#pragma unroll
    for (int n = 0; n < 2; ++n) { acc1[m][n] = zero; acc3[m][n] = zero; }

  int r0 = tid >> 3;
  int csw = ((tid & 7) ^ (r0 & 7)) * 8;    // pre-swizzled src col (elements)
  int dst0 = tid * 16;

  const unsigned short* pa[4];   // A halves h=0,1 x q=0,1
  const unsigned short* pb1[2];
  const unsigned short* pb3[2];
  {
    const unsigned short* Ab  = xg + (size_t)mrow0 * HDIM;
    const unsigned short* B1b = wc1 + ((size_t)e * Fc + fl0) * HDIM;
    const unsigned short* B3b = wc3 + ((size_t)e * Fc + fl0) * HDIM;
#pragma unroll
    for (int h = 0; h < 2; ++h)
#pragma unroll
      for (int q = 0; q < 2; ++q)
        pa[h * 2 + q] = Ab + (size_t)(h * 128 + q * 64 + r0) * HDIM + csw;
#pragma unroll
    for (int q = 0; q < 2; ++q) {
      pb1[q] = B1b + (size_t)(q * 64 + r0) * HDIM + csw;
      pb3[q] = B3b + (size_t)(q * 64 + r0) * HDIM + csw;
    }
  }

  auto STAGE_A = [&](int buf) {   // 4 loads
    char* b = lds + buf * 65536;
#pragma unroll
    for (int i = 0; i < 4; ++i) {
      gload_lds16(pa[i], b + (i >> 1) * 16384 + (i & 1) * 8192 + dst0);
      pa[i] += 64;
    }
  };
  auto STAGE_B = [&](int buf) {   // 4 loads
    char* b = lds + buf * 65536;
#pragma unroll
    for (int q = 0; q < 2; ++q) {
      gload_lds16(pb1[q], b + 32768 + q * 8192 + dst0);
      pb1[q] += 64;
      gload_lds16(pb3[q], b + 49152 + q * 8192 + dst0);
      pb3[q] += 64;
    }
  };

  const int fxor = (lr & 7) << 4;
  bf16x8 b1f[2], b3f[2];

  auto PHASE = [&](int buf, int kk, int mh, bool ldB) {
    const char* bb = lds + buf * 65536;
    const char* ab = bb + wr * 16384;
    int kbyte = (kk * 64 + lg * 16) ^ fxor;
    bf16x8 af[4];
#pragma unroll
    for (int i = 0; i < 4; ++i) {
      int ra = (mh * 4 + i) * 16 + lr;
      af[i] = *reinterpret_cast<const bf16x8*>(ab + ra * 128 + kbyte);
    }
    if (ldB) {
#pragma unroll
      for (int n = 0; n < 2; ++n) {
        int off = (wc * 32 + n * 16 + lr) * 128 + kbyte;
        b1f[n] = *reinterpret_cast<const bf16x8*>(bb + 32768 + off);
        b3f[n] = *reinterpret_cast<const bf16x8*>(bb + 49152 + off);
      }
    }
    __builtin_amdgcn_s_barrier();
    asm volatile("s_waitcnt lgkmcnt(0)" ::: "memory");
    __builtin_amdgcn_sched_barrier(0);
    __builtin_amdgcn_s_setprio(1);
#pragma unroll
    for (int i = 0; i < 4; ++i)
#pragma unroll
      for (int n = 0; n < 2; ++n) {
        acc1[mh * 4 + i][n] = MFMA16(af[i], b1f[n], acc1[mh * 4 + i][n]);
        acc3[mh * 4 + i][n] = MFMA16(af[i], b3f[n], acc3[mh * 4 + i][n]);
      }
    __builtin_amdgcn_s_setprio(0);
  };

  constexpr int NT = HDIM / 64;  // 16
  STAGE_A(0); STAGE_B(0);        // 8 loads in flight; NO drain here
#pragma unroll 1
  for (int t = 0; t < NT; ++t) {
    int c = t & 1;
    bool st = (t < NT - 1);
    if (st) {
      STAGE_A(c ^ 1);  // 4 loads; newest in queue
      asm volatile("s_waitcnt vmcnt(4)" ::: "memory");   // stage(c) landed
    } else {
      asm volatile("s_waitcnt vmcnt(0)" ::: "memory");
    }
    __builtin_amdgcn_s_barrier();          // publish stage(c) to all waves
    PHASE(c, 0, 0, true);
    __builtin_amdgcn_s_barrier();
    if (st) STAGE_B(c ^ 1);
    PHASE(c, 0, 1, false);
    __builtin_amdgcn_s_barrier();
    PHASE(c, 1, 0, true);
    __builtin_amdgcn_s_barrier();
    PHASE(c, 1, 1, false);
    __builtin_amdgcn_s_barrier();          // all reads of buf c complete (WAR)
  }

  // epilogue: silu(acc1)*acc3 -> bf16 hg
#pragma unroll
  for (int m = 0; m < 8; ++m)
#pragma unroll
    for (int n = 0; n < 2; ++n) {
      int gcol = fl0 + wc * 32 + n * 16 + lr;
#pragma unroll
      for (int j = 0; j < 4; ++j) {
        int grow = mrow0 + wr * 128 + m * 16 + lg * 4 + j;
        float s1 = acc1[m][n][j];
        float s3 = acc3[m][n][j];
        float h = s1 / (1.f + __expf(-s1)) * s3;
        hg[(size_t)grow * Fc + gcol] = f2bf(h);
      }
    }
}

// ---------------------------------------------------------------------------
// gemm2: yrows(+)= hg @ wc2^T.  256M x 128N single-B, same counted-vmcnt
// schedule (4 phases x 8 MFMA), LDS 96 KB.
__global__ __launch_bounds__(512, 2) void k_gemm2(
    const unsigned short* __restrict__ hg,
    const unsigned short* __restrict__ wc2,
    float* __restrict__ yrows, const int* __restrict__ meta,
    int Fc, int first)
{
  __shared__ __attribute__((aligned(128))) char lds[98304];
  // per buffer (stride 49152): A-half0 @0, A-half1 @16384, B @32768

  int mt = blockIdx.y;
  if (mt >= meta[25]) return;
  int e = meta[32 + mt];
  int mrow0 = mt * 256;
  int hcol0 = blockIdx.x * 128;

  int tid = threadIdx.x, lane = tid & 63, wid = tid >> 6;
  int lr = lane & 15, lg = lane >> 4;
  int wr = wid >> 2, wc = wid & 3;

  f32x4 acc[8][2];
  const f32x4 zero = {0.f, 0.f, 0.f, 0.f};
#pragma unroll
  for (int m = 0; m < 8; ++m)
#pragma unroll
    for (int n = 0; n < 2; ++n) acc[m][n] = zero;

  int r0 = tid >> 3;
  int csw = ((tid & 7) ^ (r0 & 7)) * 8;
  int dst0 = tid * 16;

  const unsigned short* pa[4];
  const unsigned short* pb[2];
  {
    const unsigned short* Ab = hg + (size_t)mrow0 * Fc;
    const unsigned short* Bb = wc2 + ((size_t)e * HDIM + hcol0) * Fc;
#pragma unroll
    for (int h = 0; h < 2; ++h)
#pragma unroll
      for (int q = 0; q < 2; ++q)
        pa[h * 2 + q] = Ab + (size_t)(h * 128 + q * 64 + r0) * Fc + csw;
#pragma unroll
    for (int q = 0; q < 2; ++q)
      pb[q] = Bb + (size_t)(q * 64 + r0) * Fc + csw;
  }

  auto STAGE_A = [&](int buf) {   // 4 loads
    char* b = lds + buf * 49152;
#pragma unroll
    for (int i = 0; i < 4; ++i) {
      gload_lds16(pa[i], b + (i >> 1) * 16384 + (i & 1) * 8192 + dst0);
      pa[i] += 64;
    }
  };
  auto STAGE_B = [&](int buf) {   // 2 loads
    char* b = lds + buf * 49152;
#pragma unroll
    for (int q = 0; q < 2; ++q) {
      gload_lds16(pb[q], b + 32768 + q * 8192 + dst0);
      pb[q] += 64;
    }
  };

  const int fxor = (lr & 7) << 4;
  bf16x8 bf[2];

  auto PHASE = [&](int buf, int kk, int mh, bool ldB) {
    const char* bb = lds + buf * 49152;
    const char* ab = bb + wr * 16384;
    int kbyte = (kk * 64 + lg * 16) ^ fxor;
    bf16x8 af[4];
#pragma unroll
    for (int i = 0; i < 4; ++i) {
      int ra = (mh * 4 + i) * 16 + lr;
      af[i] = *reinterpret_cast<const bf16x8*>(ab + ra * 128 + kbyte);
    }
    if (ldB) {
#pragma unroll
      for (int n = 0; n < 2; ++n) {
        int off = (wc * 32 + n * 16 + lr) * 128 + kbyte;
        bf[n] = *reinterpret_cast<const bf16x8*>(bb + 32768 + off);
      }
    }
    __builtin_amdgcn_s_barrier();
    asm volatile("s_waitcnt lgkmcnt(0)" ::: "memory");
    __builtin_amdgcn_sched_barrier(0);
    __builtin_amdgcn_s_setprio(1);
#pragma unroll
    for (int i = 0; i < 4; ++i)
#pragma unroll
      for (int n = 0; n < 2; ++n)
        acc[mh * 4 + i][n] = MFMA16(af[i], bf[n], acc[mh * 4 + i][n]);
    __builtin_amdgcn_s_setprio(0);
  };

  int NT = Fc / 64;
  STAGE_A(0); STAGE_B(0);        // 6 loads in flight; no drain
#pragma unroll 1
  for (int t = 0; t < NT; ++t) {
    int c = t & 1;
    bool st = (t < NT - 1);
    if (st) {
      STAGE_A(c ^ 1);
      asm volatile("s_waitcnt vmcnt(4)" ::: "memory");
    } else {
      asm volatile("s_waitcnt vmcnt(0)" ::: "memory");
    }
    __builtin_amdgcn_s_barrier();
    PHASE(c, 0, 0, true);
    __builtin_amdgcn_s_barrier();
    if (st) STAGE_B(c ^ 1);
    PHASE(c, 0, 1, false);
    __builtin_amdgcn_s_barrier();
    PHASE(c, 1, 0, true);
    __builtin_amdgcn_s_barrier();
    PHASE(c, 1, 1, false);
    __builtin_amdgcn_s_barrier();
  }

#pragma unroll
  for (int m = 0; m < 8; ++m)
#pragma unroll
    for (int n = 0; n < 2; ++n) {
      int gcol = hcol0 + wc * 32 + n * 16 + lr;
#pragma unroll
      for (int j = 0; j < 4; ++j) {
        int grow = mrow0 + wr * 128 + m * 16 + lg * 4 + j;
        float* yp = yrows + (size_t)grow * HDIM + gcol;
        float v = acc[m][n][j];
        if (first) *yp = v; else *yp += v;
      }
    }
}

__global__ __launch_bounds__(256) void k_combine(
    const float* __restrict__ yrows, const int* __restrict__ pair_row,
    const float* __restrict__ wts, float* __restrict__ out)
{
  int t = blockIdx.x * 4 + (threadIdx.x >> 6);
  int lane = threadIdx.x & 63;
  if (t >= T_TOK) return;
  int r0 = pair_row[t * 2], r1 = pair_row[t * 2 + 1];
  float w0 = (r0 >= 0) ? wts[t * 2] : 0.f;
  float w1 = (r1 >= 0) ? wts[t * 2 + 1] : 0.f;
  const float* y0 = yrows + (size_t)(r0 >= 0 ? r0 : 0) * HDIM;
  const float* y1 = yrows + (size_t)(r1 >= 0 ? r1 : 0) * HDIM;
  float* op = out + (size_t)t * HDIM;
#pragma unroll
  for (int it = 0; it < 4; ++it) {
    int base = it * 256 + lane * 4;
    float4 a = *reinterpret_cast<const float4*>(y0 + base);
    float4 b = *reinterpret_cast<const float4*>(y1 + base);
    float4 r{w0 * a.x + w1 * b.x, w0 * a.y + w1 * b.y,
             w0 * a.z + w1 * b.z, w0 * a.w + w1 * b.w};
    *reinterpret_cast<float4*>(op + base) = r;
  }
}

}  // namespace

extern "C" void kernel_launch(void* const* d_in, const int* in_sizes, int n_in,
                              void* d_out, int out_size, void* d_ws, size_t ws_size,
                              hipStream_t stream)
{
  const float* x   = (const float*)d_in[0];
  const float* gw  = (const float*)d_in[1];
  const float* gw2 = (const float*)d_in[2];
  const float* w1  = (const float*)d_in[3];
  const float* w2  = (const float*)d_in[4];
  const float* w3  = (const float*)d_in[5];
  float* out = (float*)d_out;
  float* logits_out = out + (size_t)T_TOK * HDIM;

  char* p = (char*)d_ws;
  int* meta = (int*)p;            p += 1024;
  int* sel = (int*)p;             p += T_TOK * 2 * sizeof(int);
  float* wts = (float*)p;         p += T_TOK * 2 * sizeof(float);
  int* pair_row = (int*)p;        p += T_TOK * 2 * sizeof(int);
  unsigned short* xg = (unsigned short*)p;  p += (size_t)CAP_ROWS * HDIM * 2;
  float* yrows = (float*)p;                 p += (size_t)CAP_ROWS * HDIM * 4;
  size_t fixed = (size_t)(p - (char*)d_ws);

  // per-chunk: wc1 = wc3 = wc2 = 16384*Fc bytes; hg = 36864*Fc bytes.
  int nf = 28;
  const int opts[6] = {1, 2, 4, 7, 14, 28};
  for (int i = 0; i < 6; ++i) {
    size_t Fc_i = FDIM / opts[i];
    size_t need = fixed + 3 * 16384 * Fc_i + (size_t)CAP_ROWS * Fc_i * 2;
    if (need <= ws_size) { nf = opts[i]; break; }
  }
  int Fc = FDIM / nf;

  unsigned short* wc1 = (unsigned short*)p;  p += (size_t)16384 * Fc;
  unsigned short* wc3 = (unsigned short*)p;  p += (size_t)16384 * Fc;
  unsigned short* wc2 = (unsigned short*)p;  p += (size_t)16384 * Fc;
  unsigned short* hg  = (unsigned short*)p;

  k_router<<<T_TOK / 4, 256, 0, stream>>>(x, gw, gw2, logits_out, sel, wts);
  k_histseg<<<1, 256, 0, stream>>>(sel, meta);
  k_zeropad<<<2048, 256, 0, stream>>>(meta, xg);
  k_scatter<<<T_TOK * 2 / 256, 256, 0, stream>>>(x, sel, meta, pair_row, xg);

  long long total = 8LL * Fc * HDIM;
  int ncb = (int)(total / 8 / 256);
  for (int c = 0; c < nf; ++c) {
    long long c0 = (long long)c * Fc;
    k_conv3<<<dim3(ncb, 3), 256, 0, stream>>>(
        w1 + c0 * HDIM, w3 + c0 * HDIM, w2 + c0, wc1, wc3, wc2,
        total, (long long)Fc * HDIM, (long long)FDIM * HDIM,
        (long long)Fc, (long long)FDIM);

    k_gemm1<<<dim3(Fc / 128, MAXMT), 512, 0, stream>>>(xg, wc1, wc3, hg, meta, Fc);
    k_gemm2<<<dim3(HDIM / 128, MAXMT), 512, 0, stream>>>(hg, wc2, yrows, meta, Fc, c == 0 ? 1 : 0);
  }
  k_combine<<<T_TOK / 4, 256, 0, stream>>>(yrows, pair_row, wts, out);
}

// Round 9
// 530.042 us; speedup vs baseline: 1.0356x; 1.0141x over previous
//
#include <hip/hip_runtime.h>
#include <hip/hip_bf16.h>

namespace {

constexpr int T_TOK = 8192;      // B*S
constexpr int HDIM  = 1024;
constexpr int FDIM  = 3584;
constexpr int CAP_ROWS = 18432;  // T*K + 8*256 pad
constexpr int MAXMT = CAP_ROWS / 256;  // 72

typedef __bf16 bf16x8 __attribute__((ext_vector_type(8)));
typedef float  f32x4  __attribute__((ext_vector_type(4)));

__device__ inline unsigned short f2bf(float f) {
  union { float f; unsigned u; } a; a.f = f;
  unsigned r = a.u + 0x7fffu + ((a.u >> 16) & 1u);   // RTN-even
  return (unsigned short)(r >> 16);
}

typedef const __attribute__((address_space(1))) void* gptr_t;
typedef __attribute__((address_space(3))) void* lptr_t;
__device__ inline void gload_lds16(const void* g, void* l) {
  __builtin_amdgcn_global_load_lds((gptr_t)g, (lptr_t)l, 16, 0, 0);
}

#define MFMA16(a, b, c) __builtin_amdgcn_mfma_f32_16x16x32_bf16(a, b, c, 0, 0, 0)

// meta layout (ints): [0..7] cnt, [8..15] cnt2, [16..23] seg off (rows),
// [24] total padded rows, [25] ntiles(256), [32..103] tile->expert
__global__ __launch_bounds__(256) void k_router(
    const float* __restrict__ x, const float* __restrict__ gw,
    const float* __restrict__ gw2, float* __restrict__ logits_out,
    int* __restrict__ sel, float* __restrict__ wts)
{
  int t = blockIdx.x * 4 + (threadIdx.x >> 6);
  int lane = threadIdx.x & 63;
  if (t >= T_TOK) return;
  const float* xr = x + (size_t)t * HDIM;
  float acc[10];
#pragma unroll
  for (int e = 0; e < 10; ++e) acc[e] = 0.f;
#pragma unroll
  for (int it = 0; it < 4; ++it) {
    int base = it * 256 + lane * 4;
    float4 xv = *reinterpret_cast<const float4*>(xr + base);
#pragma unroll
    for (int e = 0; e < 8; ++e) {
      float4 g = *reinterpret_cast<const float4*>(gw + e * HDIM + base);
      acc[e] += xv.x * g.x + xv.y * g.y + xv.z * g.z + xv.w * g.w;
    }
#pragma unroll
    for (int e = 0; e < 2; ++e) {
      float4 g = *reinterpret_cast<const float4*>(gw2 + e * HDIM + base);
      acc[8 + e] += xv.x * g.x + xv.y * g.y + xv.z * g.z + xv.w * g.w;
    }
  }
#pragma unroll
  for (int e = 0; e < 10; ++e) {
#pragma unroll
    for (int off = 32; off > 0; off >>= 1)
      acc[e] += __shfl_xor(acc[e], off, 64);
  }
  if (lane == 0) {
    float* lo = logits_out + (size_t)t * 10;
#pragma unroll
    for (int e = 0; e < 10; ++e) lo[e] = acc[e];
    float mx = acc[0];
#pragma unroll
    for (int e = 1; e < 10; ++e) mx = fmaxf(mx, acc[e]);
    float p[10], s = 0.f;
#pragma unroll
    for (int e = 0; e < 10; ++e) { p[e] = __expf(acc[e] - mx); s += p[e]; }
    float inv = 1.f / s;
#pragma unroll
    for (int e = 0; e < 10; ++e) p[e] *= inv;
    int i0 = 0;
    for (int e = 1; e < 10; ++e) if (p[e] > p[i0]) i0 = e;
    int i1 = (i0 == 0) ? 1 : 0;
    for (int e = 0; e < 10; ++e) if (e != i0 && p[e] > p[i1]) i1 = e;
    float w0 = p[i0], w1 = p[i1];
    bool r0 = i0 < 8, r1 = i1 < 8;
    float den = (r0 ? w0 : 0.f) + (r1 ? w1 : 0.f);
    if (den == 0.f) den = 1.f;
    sel[t * 2]     = i0; wts[t * 2]     = r0 ? w0 / den : 0.f;
    sel[t * 2 + 1] = i1; wts[t * 2 + 1] = r1 ? w1 / den : 0.f;
  }
}

// Fused histogram + segment setup (single block), 256-row padding.
__global__ __launch_bounds__(256) void k_histseg(
    const int* __restrict__ sel, int* __restrict__ meta)
{
  __shared__ int part[256][8];
  __shared__ int s_tile0[9];
  int tid = threadIdx.x;
  int c[8];
#pragma unroll
  for (int e = 0; e < 8; ++e) c[e] = 0;
  for (int i = 0; i < 64; ++i) {
    int v = sel[i * 256 + tid];
#pragma unroll
    for (int e = 0; e < 8; ++e) c[e] += (v == e);
  }
#pragma unroll
  for (int e = 0; e < 8; ++e) part[tid][e] = c[e];
  __syncthreads();
  for (int s = 128; s >= 1; s >>= 1) {
    if (tid < s) {
#pragma unroll
      for (int e = 0; e < 8; ++e) part[tid][e] += part[tid + s][e];
    }
    __syncthreads();
  }
  if (tid == 0) {
    int off = 0;
    for (int e = 0; e < 8; ++e) {
      int cnt = part[0][e];
      meta[e] = cnt;
      meta[8 + e] = 0;
      meta[16 + e] = off;
      s_tile0[e] = off >> 8;
      off += (cnt + 255) & ~255;
    }
    meta[24] = off;
    meta[25] = off >> 8;
    s_tile0[8] = off >> 8;
  }
  __syncthreads();
  int nt = s_tile0[8];
  if (tid < nt) {
    int e = 0;
    while (s_tile0[e + 1] <= tid) ++e;
    meta[32 + tid] = e;
  }
}

__global__ __launch_bounds__(256) void k_zeropad(
    const int* __restrict__ meta, unsigned short* __restrict__ xg)
{
  int e = blockIdx.x >> 8, r = blockIdx.x & 255;
  int c = meta[e];
  int pad = (c + 255) & ~255;
  if (c + r >= pad) return;
  size_t row = (size_t)meta[16 + e] + c + r;
  reinterpret_cast<ushort4*>(xg + row * HDIM)[threadIdx.x] = ushort4{0, 0, 0, 0};
}

// Block-aggregated scatter (unchanged).
__global__ __launch_bounds__(256) void k_scatter(
    const float* __restrict__ x, const int* __restrict__ sel,
    int* __restrict__ meta, int* __restrict__ pair_row,
    unsigned short* __restrict__ xg)
{
  __shared__ int s_cnt[8];
  __shared__ int s_base[8];
  __shared__ int s_row[256];
  int tid = threadIdx.x;
  int pair0 = blockIdx.x * 256;
  if (tid < 8) s_cnt[tid] = 0;
  __syncthreads();
  int e = sel[pair0 + tid];
  int rank = -1;
  if (e < 8) rank = atomicAdd(&s_cnt[e], 1);
  __syncthreads();
  if (tid < 8) {
    int c = s_cnt[tid];
    s_base[tid] = c > 0 ? atomicAdd(&meta[8 + tid], c) : 0;
  }
  __syncthreads();
  int row = (e < 8) ? meta[16 + e] + s_base[e] + rank : -1;
  pair_row[pair0 + tid] = row;
  s_row[tid] = row;
  __syncthreads();
  int wid = tid >> 6, lane = tid & 63;
  for (int i = wid; i < 256; i += 4) {
    int r = s_row[i];
    if (r < 0) continue;
    const float* xr = x + (size_t)((pair0 + i) >> 1) * HDIM;
    unsigned short* dst = xg + (size_t)r * HDIM;
#pragma unroll
    for (int it = 0; it < 4; ++it) {
      int base = it * 256 + lane * 4;
      float4 v = *reinterpret_cast<const float4*>(xr + base);
      ushort4 o{f2bf(v.x), f2bf(v.y), f2bf(v.z), f2bf(v.w)};
      *reinterpret_cast<ushort4*>(dst + base) = o;
    }
  }
}

// fp32 -> bf16 weight-chunk convert (unchanged).
__global__ __launch_bounds__(256) void k_conv3(
    const float* __restrict__ s1, const float* __restrict__ s3,
    const float* __restrict__ s2,
    unsigned short* __restrict__ d1, unsigned short* __restrict__ d3,
    unsigned short* __restrict__ d2,
    long long total, long long rl13, long long ss13,
    long long rl2, long long ss2)
{
  long long i = ((long long)blockIdx.x * 256 + threadIdx.x) * 8;
  if (i >= total) return;
  const float* src; unsigned short* dst; long long rowlen, sstride;
  if (blockIdx.y == 0)      { src = s1; dst = d1; rowlen = rl13; sstride = ss13; }
  else if (blockIdx.y == 1) { src = s3; dst = d3; rowlen = rl13; sstride = ss13; }
  else                      { src = s2; dst = d2; rowlen = rl2;  sstride = ss2;  }
  const float* sp;
  if (rowlen == sstride) {
    sp = src + i;
  } else {
    long long r = i / rowlen, c = i - r * rowlen;
    sp = src + r * sstride + c;
  }
  float4 a = reinterpret_cast<const float4*>(sp)[0];
  float4 b = reinterpret_cast<const float4*>(sp)[1];
  ushort4* d = reinterpret_cast<ushort4*>(dst + i);
  d[0] = ushort4{f2bf(a.x), f2bf(a.y), f2bf(a.z), f2bf(a.w)};
  d[1] = ushort4{f2bf(b.x), f2bf(b.y), f2bf(b.z), f2bf(b.w)};
}

// ---------------------------------------------------------------------------
// gemm1: hg = silu(xg @ wc1^T) * (xg @ wc3^T).  256M x 128N fused dual-B,
// 8 waves, BK=64, 2-buffer LDS. Minimal sync: per K-tile {STAGE(next, 8
// loads) -> counted vmcnt(8) -> barrier -> flat compiler-scheduled compute
// (no intra-tile barriers: all phases read the same buffer) -> barrier}.
// Compiler inserts fine-grained lgkmcnt between ds_read and MFMA; waves skew
// between the two barriers so LDS reads overlap other waves' MFMA.
__global__ __launch_bounds__(512, 2) void k_gemm1(
    const unsigned short* __restrict__ xg,
    const unsigned short* __restrict__ wc1,
    const unsigned short* __restrict__ wc3,
    unsigned short* __restrict__ hg,
    const int* __restrict__ meta, int Fc)
{
  __shared__ __attribute__((aligned(128))) char lds[131072];
  // per buffer (stride 65536): A-half0 @0, A-half1 @16384, B1 @32768, B3 @49152

  int mt = blockIdx.y;
  if (mt >= meta[25]) return;
  int e = meta[32 + mt];
  int mrow0 = mt * 256;
  int fl0 = blockIdx.x * 128;

  int tid = threadIdx.x, lane = tid & 63, wid = tid >> 6;
  int lr = lane & 15, lg = lane >> 4;
  int wr = wid >> 2, wc = wid & 3;

  f32x4 acc1[8][2], acc3[8][2];
  const f32x4 zero = {0.f, 0.f, 0.f, 0.f};
#pragma unroll
  for (int m = 0; m < 8; ++m)
#pragma unroll
    for (int n = 0; n < 2; ++n) { acc1[m][n] = zero; acc3[m][n] = zero; }

  int r0 = tid >> 3;
  int csw = ((tid & 7) ^ (r0 & 7)) * 8;    // pre-swizzled src col (elements)
  int dst0 = tid * 16;

  const unsigned short* pa[4];   // A halves h=0,1 x q=0,1
  const unsigned short* pb1[2];
  const unsigned short* pb3[2];
  {
    const unsigned short* Ab  = xg + (size_t)mrow0 * HDIM;
    const unsigned short* B1b = wc1 + ((size_t)e * Fc + fl0) * HDIM;
    const unsigned short* B3b = wc3 + ((size_t)e * Fc + fl0) * HDIM;
#pragma unroll
    for (int h = 0; h < 2; ++h)
#pragma unroll
      for (int q = 0; q < 2; ++q)
        pa[h * 2 + q] = Ab + (size_t)(h * 128 + q * 64 + r0) * HDIM + csw;
#pragma unroll
    for (int q = 0; q < 2; ++q) {
      pb1[q] = B1b + (size_t)(q * 64 + r0) * HDIM + csw;
      pb3[q] = B3b + (size_t)(q * 64 + r0) * HDIM + csw;
    }
  }

  auto STAGE = [&](int buf) {   // 8 loads
    char* b = lds + buf * 65536;
#pragma unroll
    for (int i = 0; i < 4; ++i) {
      gload_lds16(pa[i], b + (i >> 1) * 16384 + (i & 1) * 8192 + dst0);
      pa[i] += 64;
    }
#pragma unroll
    for (int q = 0; q < 2; ++q) {
      gload_lds16(pb1[q], b + 32768 + q * 8192 + dst0);
      pb1[q] += 64;
      gload_lds16(pb3[q], b + 49152 + q * 8192 + dst0);
      pb3[q] += 64;
    }
  };

  const int fxor = (lr & 7) << 4;

  constexpr int NT = HDIM / 64;  // 16
  STAGE(0);                      // 8 loads in flight
#pragma unroll 1
  for (int t = 0; t < NT; ++t) {
    int c = t & 1;
    if (t < NT - 1) {
      STAGE(c ^ 1);                                      // +8 -> 16 outstanding
      asm volatile("s_waitcnt vmcnt(8)" ::: "memory");   // tile-t loads landed
    } else {
      asm volatile("s_waitcnt vmcnt(0)" ::: "memory");
    }
    asm volatile("s_barrier" ::: "memory");              // publish stage(c)

    const char* bb = lds + c * 65536;
    const char* ab = bb + wr * 16384;
#pragma unroll
    for (int kk = 0; kk < 2; ++kk) {
      int kbyte = (kk * 64 + lg * 16) ^ fxor;
      bf16x8 b1f[2], b3f[2];
#pragma unroll
      for (int n = 0; n < 2; ++n) {
        int off = (wc * 32 + n * 16 + lr) * 128 + kbyte;
        b1f[n] = *reinterpret_cast<const bf16x8*>(bb + 32768 + off);
        b3f[n] = *reinterpret_cast<const bf16x8*>(bb + 49152 + off);
      }
#pragma unroll
      for (int m = 0; m < 8; ++m) {
        bf16x8 af = *reinterpret_cast<const bf16x8*>(ab + (m * 16 + lr) * 128 + kbyte);
#pragma unroll
        for (int n = 0; n < 2; ++n) {
          acc1[m][n] = MFMA16(af, b1f[n], acc1[m][n]);
          acc3[m][n] = MFMA16(af, b3f[n], acc3[m][n]);
        }
      }
    }
    asm volatile("s_barrier" ::: "memory");              // WAR: done reading c
  }

  // epilogue: silu(acc1)*acc3 -> bf16 hg
#pragma unroll
  for (int m = 0; m < 8; ++m)
#pragma unroll
    for (int n = 0; n < 2; ++n) {
      int gcol = fl0 + wc * 32 + n * 16 + lr;
#pragma unroll
      for (int j = 0; j < 4; ++j) {
        int grow = mrow0 + wr * 128 + m * 16 + lg * 4 + j;
        float s1 = acc1[m][n][j];
        float s3 = acc3[m][n][j];
        float h = s1 / (1.f + __expf(-s1)) * s3;
        hg[(size_t)grow * Fc + gcol] = f2bf(h);
      }
    }
}

// ---------------------------------------------------------------------------
// gemm2: yrows(+)= hg @ wc2^T.  256M x 128N single-B, same minimal-sync
// counted-vmcnt loop (6 loads/tile), LDS 96 KB.
__global__ __launch_bounds__(512, 2) void k_gemm2(
    const unsigned short* __restrict__ hg,
    const unsigned short* __restrict__ wc2,
    float* __restrict__ yrows, const int* __restrict__ meta,
    int Fc, int first)
{
  __shared__ __attribute__((aligned(128))) char lds[98304];
  // per buffer (stride 49152): A-half0 @0, A-half1 @16384, B @32768

  int mt = blockIdx.y;
  if (mt >= meta[25]) return;
  int e = meta[32 + mt];
  int mrow0 = mt * 256;
  int hcol0 = blockIdx.x * 128;

  int tid = threadIdx.x, lane = tid & 63, wid = tid >> 6;
  int lr = lane & 15, lg = lane >> 4;
  int wr = wid >> 2, wc = wid & 3;

  f32x4 acc[8][2];
  const f32x4 zero = {0.f, 0.f, 0.f, 0.f};
#pragma unroll
  for (int m = 0; m < 8; ++m)
#pragma unroll
    for (int n = 0; n < 2; ++n) acc[m][n] = zero;

  int r0 = tid >> 3;
  int csw = ((tid & 7) ^ (r0 & 7)) * 8;
  int dst0 = tid * 16;

  const unsigned short* pa[4];
  const unsigned short* pb[2];
  {
    const unsigned short* Ab = hg + (size_t)mrow0 * Fc;
    const unsigned short* Bb = wc2 + ((size_t)e * HDIM + hcol0) * Fc;
#pragma unroll
    for (int h = 0; h < 2; ++h)
#pragma unroll
      for (int q = 0; q < 2; ++q)
        pa[h * 2 + q] = Ab + (size_t)(h * 128 + q * 64 + r0) * Fc + csw;
#pragma unroll
    for (int q = 0; q < 2; ++q)
      pb[q] = Bb + (size_t)(q * 64 + r0) * Fc + csw;
  }

  auto STAGE = [&](int buf) {   // 6 loads
    char* b = lds + buf * 49152;
#pragma unroll
    for (int i = 0; i < 4; ++i) {
      gload_lds16(pa[i], b + (i >> 1) * 16384 + (i & 1) * 8192 + dst0);
      pa[i] += 64;
    }
#pragma unroll
    for (int q = 0; q < 2; ++q) {
      gload_lds16(pb[q], b + 32768 + q * 8192 + dst0);
      pb[q] += 64;
    }
  };

  const int fxor = (lr & 7) << 4;

  int NT = Fc / 64;
  STAGE(0);
#pragma unroll 1
  for (int t = 0; t < NT; ++t) {
    int c = t & 1;
    if (t < NT - 1) {
      STAGE(c ^ 1);
      asm volatile("s_waitcnt vmcnt(6)" ::: "memory");
    } else {
      asm volatile("s_waitcnt vmcnt(0)" ::: "memory");
    }
    asm volatile("s_barrier" ::: "memory");

    const char* bb = lds + c * 49152;
    const char* ab = bb + wr * 16384;
#pragma unroll
    for (int kk = 0; kk < 2; ++kk) {
      int kbyte = (kk * 64 + lg * 16) ^ fxor;
      bf16x8 bf[2];
#pragma unroll
      for (int n = 0; n < 2; ++n) {
        int off = (wc * 32 + n * 16 + lr) * 128 + kbyte;
        bf[n] = *reinterpret_cast<const bf16x8*>(bb + 32768 + off);
      }
#pragma unroll
      for (int m = 0; m < 8; ++m) {
        bf16x8 af = *reinterpret_cast<const bf16x8*>(ab + (m * 16 + lr) * 128 + kbyte);
#pragma unroll
        for (int n = 0; n < 2; ++n)
          acc[m][n] = MFMA16(af, bf[n], acc[m][n]);
      }
    }
    asm volatile("s_barrier" ::: "memory");
  }

#pragma unroll
  for (int m = 0; m < 8; ++m)
#pragma unroll
    for (int n = 0; n < 2; ++n) {
      int gcol = hcol0 + wc * 32 + n * 16 + lr;
#pragma unroll
      for (int j = 0; j < 4; ++j) {
        int grow = mrow0 + wr * 128 + m * 16 + lg * 4 + j;
        float* yp = yrows + (size_t)grow * HDIM + gcol;
        float v = acc[m][n][j];
        if (first) *yp = v; else *yp += v;
      }
    }
}

__global__ __launch_bounds__(256) void k_combine(
    const float* __restrict__ yrows, const int* __restrict__ pair_row,
    const float* __restrict__ wts, float* __restrict__ out)
{
  int t = blockIdx.x * 4 + (threadIdx.x >> 6);
  int lane = threadIdx.x & 63;
  if (t >= T_TOK) return;
  int r0 = pair_row[t * 2], r1 = pair_row[t * 2 + 1];
  float w0 = (r0 >= 0) ? wts[t * 2] : 0.f;
  float w1 = (r1 >= 0) ? wts[t * 2 + 1] : 0.f;
  const float* y0 = yrows + (size_t)(r0 >= 0 ? r0 : 0) * HDIM;
  const float* y1 = yrows + (size_t)(r1 >= 0 ? r1 : 0) * HDIM;
  float* op = out + (size_t)t * HDIM;
#pragma unroll
  for (int it = 0; it < 4; ++it) {
    int base = it * 256 + lane * 4;
    float4 a = *reinterpret_cast<const float4*>(y0 + base);
    float4 b = *reinterpret_cast<const float4*>(y1 + base);
    float4 r{w0 * a.x + w1 * b.x, w0 * a.y + w1 * b.y,
             w0 * a.z + w1 * b.z, w0 * a.w + w1 * b.w};
    *reinterpret_cast<float4*>(op + base) = r;
  }
}

}  // namespace

extern "C" void kernel_launch(void* const* d_in, const int* in_sizes, int n_in,
                              void* d_out, int out_size, void* d_ws, size_t ws_size,
                              hipStream_t stream)
{
  const float* x   = (const float*)d_in[0];
  const float* gw  = (const float*)d_in[1];
  const float* gw2 = (const float*)d_in[2];
  const float* w1  = (const float*)d_in[3];
  const float* w2  = (const float*)d_in[4];
  const float* w3  = (const float*)d_in[5];
  float* out = (float*)d_out;
  float* logits_out = out + (size_t)T_TOK * HDIM;

  char* p = (char*)d_ws;
  int* meta = (int*)p;            p += 1024;
  int* sel = (int*)p;             p += T_TOK * 2 * sizeof(int);
  float* wts = (float*)p;         p += T_TOK * 2 * sizeof(float);
  int* pair_row = (int*)p;        p += T_TOK * 2 * sizeof(int);
  unsigned short* xg = (unsigned short*)p;  p += (size_t)CAP_ROWS * HDIM * 2;
  float* yrows = (float*)p;                 p += (size_t)CAP_ROWS * HDIM * 4;
  size_t fixed = (size_t)(p - (char*)d_ws);

  // per-chunk: wc1 = wc3 = wc2 = 16384*Fc bytes; hg = 36864*Fc bytes.
  int nf = 28;
  const int opts[6] = {1, 2, 4, 7, 14, 28};
  for (int i = 0; i < 6; ++i) {
    size_t Fc_i = FDIM / opts[i];
    size_t need = fixed + 3 * 16384 * Fc_i + (size_t)CAP_ROWS * Fc_i * 2;
    if (need <= ws_size) { nf = opts[i]; break; }
  }
  int Fc = FDIM / nf;

  unsigned short* wc1 = (unsigned short*)p;  p += (size_t)16384 * Fc;
  unsigned short* wc3 = (unsigned short*)p;  p += (size_t)16384 * Fc;
  unsigned short* wc2 = (unsigned short*)p;  p += (size_t)16384 * Fc;
  unsigned short* hg  = (unsigned short*)p;

  k_router<<<T_TOK / 4, 256, 0, stream>>>(x, gw, gw2, logits_out, sel, wts);
  k_histseg<<<1, 256, 0, stream>>>(sel, meta);
  k_zeropad<<<2048, 256, 0, stream>>>(meta, xg);
  k_scatter<<<T_TOK * 2 / 256, 256, 0, stream>>>(x, sel, meta, pair_row, xg);

  long long total = 8LL * Fc * HDIM;
  int ncb = (int)(total / 8 / 256);
  for (int c = 0; c < nf; ++c) {
    long long c0 = (long long)c * Fc;
    k_conv3<<<dim3(ncb, 3), 256, 0, stream>>>(
        w1 + c0 * HDIM, w3 + c0 * HDIM, w2 + c0, wc1, wc3, wc2,
        total, (long long)Fc * HDIM, (long long)FDIM * HDIM,
        (long long)Fc, (long long)FDIM);

    k_gemm1<<<dim3(Fc / 128, MAXMT), 512, 0, stream>>>(xg, wc1, wc3, hg, meta, Fc);
    k_gemm2<<<dim3(HDIM / 128, MAXMT), 512, 0, stream>>>(hg, wc2, yrows, meta, Fc, c == 0 ? 1 : 0);
  }
  k_combine<<<T_TOK / 4, 256, 0, stream>>>(yrows, pair_row, wts, out);
}